// Round 1
// baseline (520.602 us; speedup 1.0000x reference)
//
#include <hip/hip_runtime.h>

// CrossAttention: B=4, L=256, D=2048, LE=2048, DE=1024, H=16, HD=128
// All GEMMs in bf16 MFMA (16x16x32), fp32 accum, fp32 softmax/rope.

#define B_ 4
#define L_ 256
#define D_ 2048
#define LE_ 2048
#define DE_ 1024
#define H_ 16
#define HD_ 128

using f32x4  = __attribute__((ext_vector_type(4))) float;
using bf16x8 = __attribute__((ext_vector_type(8))) short;

__device__ __forceinline__ unsigned short f2bf(float f) {
    union { float f; unsigned int u; } v; v.f = f;
    unsigned int r = v.u + 0x7fffu + ((v.u >> 16) & 1u);   // RNE
    return (unsigned short)(r >> 16);
}
__device__ __forceinline__ float b2f(unsigned short h) {
    union { unsigned int u; float f; } v; v.u = ((unsigned int)h) << 16;
    return v.f;
}

__device__ __forceinline__ void load_lds16(const void* g, void* l) {
    __builtin_amdgcn_global_load_lds((const __attribute__((address_space(1))) void*)g,
                                     (__attribute__((address_space(3))) void*)l, 16, 0, 0);
}

// ---------------- elementwise cast fp32 -> bf16 (vec4) ----------------
__global__ void cast_f32_bf16(const float* __restrict__ in, unsigned short* __restrict__ out, int n) {
    int i = (blockIdx.x * 256 + threadIdx.x) * 4;
    if (i < n) {
        float4 v = *(const float4*)(in + i);
        ushort4 o;
        o.x = f2bf(v.x); o.y = f2bf(v.y); o.z = f2bf(v.z); o.w = f2bf(v.w);
        *(ushort4*)(out + i) = o;
    }
}

// ---------------- tiled transpose fp32[R,C] -> bf16[C,R] ----------------
__global__ void transpose_f32_bf16(const float* __restrict__ in, unsigned short* __restrict__ out,
                                   int R, int C) {
    __shared__ float t[32][33];
    int r0 = blockIdx.y * 32, c0 = blockIdx.x * 32;
    int tx = threadIdx.x, ty = threadIdx.y;            // block (32,8)
    #pragma unroll
    for (int i = 0; i < 32; i += 8) t[ty + i][tx] = in[(long)(r0 + ty + i) * C + c0 + tx];
    __syncthreads();
    #pragma unroll
    for (int i = 0; i < 32; i += 8) out[(long)(c0 + ty + i) * R + r0 + tx] = f2bf(t[tx][ty + i]);
}

// ---------------- tiled transpose bf16[R,C] -> bf16[C,R], batched (z) ----------------
__global__ void transpose_bf16_batched(const unsigned short* __restrict__ in,
                                       unsigned short* __restrict__ out, int R, int C) {
    __shared__ unsigned short t[32][33];
    long zo = (long)blockIdx.z * R * C;
    int r0 = blockIdx.y * 32, c0 = blockIdx.x * 32;
    int tx = threadIdx.x, ty = threadIdx.y;            // block (32,8)
    #pragma unroll
    for (int i = 0; i < 32; i += 8) t[ty + i][tx] = in[zo + (long)(r0 + ty + i) * C + c0 + tx];
    __syncthreads();
    #pragma unroll
    for (int i = 0; i < 32; i += 8) out[zo + (long)(c0 + ty + i) * R + r0 + tx] = t[tx][ty + i];
}

// ---------------- in-place RoPE on Q_bf [B*H, L, HD], folds 1/sqrt(HD) ----------------
__global__ void rope_inplace(unsigned short* __restrict__ Q) {
    int idx = blockIdx.x * 256 + threadIdx.x;          // B*H*L*(HD/2) = 1,048,576
    int p  = idx & 63;                                 // pair index 0..63
    int l  = (idx >> 6) & 255;
    int bh = idx >> 14;
    long base = (((long)bh * L_ + l) << 7) + 2 * p;
    float q1 = b2f(Q[base]), q2 = b2f(Q[base + 1]);
    float inv = powf(10000.0f, -(float)p * (1.0f / 64.0f));
    float ang = (float)l * inv;
    float s, c;
    sincosf(ang, &s, &c);
    const float sc = 0.08838834764831845f;             // 1/sqrt(128)
    Q[base]     = f2bf((q1 * c - q2 * s) * sc);
    Q[base + 1] = f2bf((q1 * s + q2 * c) * sc);
}

// ---------------- row softmax, in-place on bf16 rows of 2048 ----------------
__launch_bounds__(256)
__global__ void softmax_rows(unsigned short* __restrict__ S) {
    long row = blockIdx.x;
    unsigned short* p = S + row * 2048;
    int t = threadIdx.x, w = t >> 6, lane = t & 63;
    float v[8];
    float mx = -1e30f;
    #pragma unroll
    for (int i = 0; i < 8; i++) { v[i] = b2f(p[t + i * 256]); mx = fmaxf(mx, v[i]); }
    #pragma unroll
    for (int o = 32; o; o >>= 1) mx = fmaxf(mx, __shfl_xor(mx, o));
    __shared__ float redm[4], reds[4];
    if (lane == 0) redm[w] = mx;
    __syncthreads();
    mx = fmaxf(fmaxf(redm[0], redm[1]), fmaxf(redm[2], redm[3]));
    float sum = 0.f;
    #pragma unroll
    for (int i = 0; i < 8; i++) { v[i] = __expf(v[i] - mx); sum += v[i]; }
    #pragma unroll
    for (int o = 32; o; o >>= 1) sum += __shfl_xor(sum, o);
    if (lane == 0) reds[w] = sum;
    __syncthreads();
    sum = reds[0] + reds[1] + reds[2] + reds[3];
    float r = 1.0f / sum;
    #pragma unroll
    for (int i = 0; i < 8; i++) p[t + i * 256] = f2bf(v[i] * r);
}

// ---------------- bf16 GEMM: C[M,N] = A[M,K] * Bt[N,K]^T (+bias), batched ----------------
// EPI 0: fp32 plain [M,N] (+bias)
// EPI 1: bf16 head relayout [(b*16+h)*rows + mrow][128] (+bias); rows = 1<<rpb_shift
// EPI 2: bf16 plain batched [z][M,N]
// EPI 3: bf16 ctx relayout: out[( (z>>4)*256 + m )*2048 + (z&15)*128 + n]
template <int EPI>
__launch_bounds__(256)
__global__ void gemm_bt(const unsigned short* __restrict__ A, const unsigned short* __restrict__ Bt,
                        const float* __restrict__ bias, void* __restrict__ out,
                        int M, int N, int K, long strideA, long strideB, int rpb_shift) {
    __shared__ __align__(16) unsigned short As[128 * 32];
    __shared__ __align__(16) unsigned short Bs[128 * 32];
    const int z = blockIdx.z;
    const unsigned short* Ab = A + (long)z * strideA;
    const unsigned short* Bb = Bt + (long)z * strideB;
    const int m0 = blockIdx.y * 128, n0 = blockIdx.x * 128;
    const int tid = threadIdx.x;
    const int w = tid >> 6, lane = tid & 63;
    const int quad = lane >> 4, l16 = lane & 15;
    const int wr = w >> 1, wc = w & 1;
    const int srow = lane >> 2;          // staging: row within 16-row chunk
    const int scol = (lane & 3) * 8;     // staging: k-offset (elements)

    f32x4 acc[4][4] = {};

    for (int k0 = 0; k0 < K; k0 += 32) {
        #pragma unroll
        for (int q = 0; q < 2; q++) {
            int ci = q * 4 + w;          // 1KB chunk id, 0..7
            int row = ci * 16 + srow;
            load_lds16(Ab + (long)(m0 + row) * K + k0 + scol, (void*)(As + ci * 512));
            load_lds16(Bb + (long)(n0 + row) * K + k0 + scol, (void*)(Bs + ci * 512));
        }
        __syncthreads();
        bf16x8 af[4], bfr[4];
        #pragma unroll
        for (int i = 0; i < 4; i++) {
            int r = wr * 64 + i * 16 + l16;
            af[i] = *(const bf16x8*)(As + r * 32 + quad * 8);
        }
        #pragma unroll
        for (int j = 0; j < 4; j++) {
            int r = wc * 64 + j * 16 + l16;
            bfr[j] = *(const bf16x8*)(Bs + r * 32 + quad * 8);
        }
        #pragma unroll
        for (int i = 0; i < 4; i++)
            #pragma unroll
            for (int j = 0; j < 4; j++)
                acc[i][j] = __builtin_amdgcn_mfma_f32_16x16x32_bf16(af[i], bfr[j], acc[i][j], 0, 0, 0);
        __syncthreads();
    }

    #pragma unroll
    for (int i = 0; i < 4; i++) {
        #pragma unroll
        for (int j = 0; j < 4; j++) {
            #pragma unroll
            for (int r = 0; r < 4; r++) {
                int m = m0 + wr * 64 + i * 16 + quad * 4 + r;
                int n = n0 + wc * 64 + j * 16 + l16;
                float v = acc[i][j][r];
                if (bias) v += bias[n];
                if constexpr (EPI == 0) {
                    ((float*)out)[(long)m * N + n] = v;
                } else if constexpr (EPI == 1) {
                    int b = m >> rpb_shift, mrow = m - (b << rpb_shift);
                    int h = n >> 7, d = n & 127;
                    long idx = ((((long)b * 16 + h) << rpb_shift) + mrow);
                    ((unsigned short*)out)[(idx << 7) + d] = f2bf(v);
                } else if constexpr (EPI == 2) {
                    ((unsigned short*)out)[(long)z * M * N + (long)m * N + n] = f2bf(v);
                } else {
                    int b = z >> 4, h = z & 15;
                    ((unsigned short*)out)[((long)(b * 256 + m)) * 2048 + h * 128 + n] = f2bf(v);
                }
            }
        }
    }
}

extern "C" void kernel_launch(void* const* d_in, const int* in_sizes, int n_in,
                              void* d_out, int out_size, void* d_ws, size_t ws_size,
                              hipStream_t stream) {
    const float* x   = (const float*)d_in[0];   // [4,256,2048]
    const float* enc = (const float*)d_in[1];   // [4,2048,1024]
    const float* Wq  = (const float*)d_in[2];   // [2048,2048]
    const float* bq  = (const float*)d_in[3];
    const float* Wk  = (const float*)d_in[4];   // [1024,2048]
    const float* bk  = (const float*)d_in[5];
    const float* Wv  = (const float*)d_in[6];   // [1024,2048]
    const float* bv  = (const float*)d_in[7];
    const float* Wo  = (const float*)d_in[8];   // [2048,2048]
    const float* bo  = (const float*)d_in[9];
    float* out = (float*)d_out;                 // [4,256,2048] fp32

    char* ws = (char*)d_ws;
    size_t o = 0;
    unsigned short* x_bf   = (unsigned short*)(ws + o); o += 2097152ULL * 2;   // [1024,2048]
    unsigned short* enc_bf = (unsigned short*)(ws + o); o += 8388608ULL * 2;   // [8192,1024]
    unsigned short* WqT    = (unsigned short*)(ws + o); o += 4194304ULL * 2;   // [2048,2048]
    unsigned short* WkT    = (unsigned short*)(ws + o); o += 2097152ULL * 2;   // [2048,1024]
    unsigned short* WvT    = (unsigned short*)(ws + o); o += 2097152ULL * 2;   // [2048,1024]
    unsigned short* WoT    = (unsigned short*)(ws + o); o += 4194304ULL * 2;   // [2048,2048]
    unsigned short* Q_bf   = (unsigned short*)(ws + o); o += 2097152ULL * 2;   // [64,256,128]
    unsigned short* K_bf   = (unsigned short*)(ws + o); o += 16777216ULL * 2;  // [64,2048,128]
    unsigned short* V_bf   = (unsigned short*)(ws + o); o += 16777216ULL * 2;  // [64,2048,128]
    unsigned short* Vt     = (unsigned short*)(ws + o); o += 16777216ULL * 2;  // [64,128,2048]
    unsigned short* S_bf   = (unsigned short*)(ws + o); o += 33554432ULL * 2;  // [64,256,2048]
    unsigned short* ctx_bf = (unsigned short*)(ws + o); o += 2097152ULL * 2;   // [1024,2048]

    dim3 tb(32, 8);

    // casts
    cast_f32_bf16<<<2048, 256, 0, stream>>>(x, x_bf, 2097152);
    cast_f32_bf16<<<8192, 256, 0, stream>>>(enc, enc_bf, 8388608);

    // weight transposes (fp32 [K,N] -> bf16 [N,K])
    transpose_f32_bf16<<<dim3(64, 64), tb, 0, stream>>>(Wq, WqT, 2048, 2048);
    transpose_f32_bf16<<<dim3(64, 32), tb, 0, stream>>>(Wk, WkT, 1024, 2048);
    transpose_f32_bf16<<<dim3(64, 32), tb, 0, stream>>>(Wv, WvT, 1024, 2048);
    transpose_f32_bf16<<<dim3(64, 64), tb, 0, stream>>>(Wo, WoT, 2048, 2048);

    // Q = x @ Wq + bq -> head layout bf16 [B,H,L,HD]
    gemm_bt<1><<<dim3(16, 8, 1), 256, 0, stream>>>(x_bf, WqT, bq, Q_bf, 1024, 2048, 2048, 0, 0, 8);
    // RoPE in place (+ fold 1/sqrt(HD))
    rope_inplace<<<4096, 256, 0, stream>>>(Q_bf);

    // K,V = enc @ Wk/Wv + b -> head layout bf16 [B,H,LE,HD]
    gemm_bt<1><<<dim3(16, 64, 1), 256, 0, stream>>>(enc_bf, WkT, bk, K_bf, 8192, 2048, 1024, 0, 0, 11);
    gemm_bt<1><<<dim3(16, 64, 1), 256, 0, stream>>>(enc_bf, WvT, bv, V_bf, 8192, 2048, 1024, 0, 0, 11);

    // V -> Vt  [B,H,HD,LE]
    transpose_bf16_batched<<<dim3(4, 64, 64), tb, 0, stream>>>(V_bf, Vt, 2048, 128);

    // S = Q @ K^T (scale folded into Q) -> bf16 [64,256,2048]
    gemm_bt<2><<<dim3(16, 2, 64), 256, 0, stream>>>(Q_bf, K_bf, nullptr, S_bf,
                                                    256, 2048, 128, 256 * 128, 2048 * 128, 0);
    // softmax rows
    softmax_rows<<<16384, 256, 0, stream>>>(S_bf);

    // ctx = P @ V -> bf16 [B,L,D] (relayout in epilogue)
    gemm_bt<3><<<dim3(1, 2, 64), 256, 0, stream>>>(S_bf, Vt, nullptr, ctx_bf,
                                                   256, 128, 2048, 256 * 2048, 128 * 2048, 0);

    // out = ctx @ Wo + bo -> fp32
    gemm_bt<0><<<dim3(16, 8, 1), 256, 0, stream>>>(ctx_bf, WoT, bo, out, 1024, 2048, 2048, 0, 0, 0);
}

// Round 2
// 520.203 us; speedup vs baseline: 1.0008x; 1.0008x over previous
//
#include <hip/hip_runtime.h>

// CrossAttention: B=4, L=256, D=2048, LE=2048, DE=1024, H=16, HD=128
// bf16 MFMA GEMMs (fp32 accum), fp32 softmax/rope.
// R2: LDS-bounce vectorized epilogues (16B stores) + PV split-K=2.

#define B_ 4
#define L_ 256
#define D_ 2048
#define LE_ 2048
#define DE_ 1024
#define H_ 16
#define HD_ 128

using f32x4  = __attribute__((ext_vector_type(4))) float;
using bf16x8 = __attribute__((ext_vector_type(8))) short;

__device__ __forceinline__ unsigned short f2bf(float f) {
    union { float f; unsigned int u; } v; v.f = f;
    unsigned int r = v.u + 0x7fffu + ((v.u >> 16) & 1u);   // RNE
    return (unsigned short)(r >> 16);
}
__device__ __forceinline__ float b2f(unsigned short h) {
    union { unsigned int u; float f; } v; v.u = ((unsigned int)h) << 16;
    return v.f;
}

__device__ __forceinline__ void load_lds16(const void* g, void* l) {
    __builtin_amdgcn_global_load_lds((const __attribute__((address_space(1))) void*)g,
                                     (__attribute__((address_space(3))) void*)l, 16, 0, 0);
}

// ---------------- elementwise cast fp32 -> bf16 (vec4) ----------------
__global__ void cast_f32_bf16(const float* __restrict__ in, unsigned short* __restrict__ out, int n) {
    int i = (blockIdx.x * 256 + threadIdx.x) * 4;
    if (i < n) {
        float4 v = *(const float4*)(in + i);
        ushort4 o;
        o.x = f2bf(v.x); o.y = f2bf(v.y); o.z = f2bf(v.z); o.w = f2bf(v.w);
        *(ushort4*)(out + i) = o;
    }
}

// ---------------- tiled transpose fp32[R,C] -> bf16[C,R] ----------------
__global__ void transpose_f32_bf16(const float* __restrict__ in, unsigned short* __restrict__ out,
                                   int R, int C) {
    __shared__ float t[32][33];
    int r0 = blockIdx.y * 32, c0 = blockIdx.x * 32;
    int tx = threadIdx.x, ty = threadIdx.y;            // block (32,8)
    #pragma unroll
    for (int i = 0; i < 32; i += 8) t[ty + i][tx] = in[(long)(r0 + ty + i) * C + c0 + tx];
    __syncthreads();
    #pragma unroll
    for (int i = 0; i < 32; i += 8) out[(long)(c0 + ty + i) * R + r0 + tx] = f2bf(t[tx][ty + i]);
}

// ---------------- tiled transpose bf16[R,C] -> bf16[C,R], batched (z) ----------------
__global__ void transpose_bf16_batched(const unsigned short* __restrict__ in,
                                       unsigned short* __restrict__ out, int R, int C) {
    __shared__ unsigned short t[32][33];
    long zo = (long)blockIdx.z * R * C;
    int r0 = blockIdx.y * 32, c0 = blockIdx.x * 32;
    int tx = threadIdx.x, ty = threadIdx.y;            // block (32,8)
    #pragma unroll
    for (int i = 0; i < 32; i += 8) t[ty + i][tx] = in[zo + (long)(r0 + ty + i) * C + c0 + tx];
    __syncthreads();
    #pragma unroll
    for (int i = 0; i < 32; i += 8) out[zo + (long)(c0 + ty + i) * R + r0 + tx] = t[tx][ty + i];
}

// ---------------- in-place RoPE on Q_bf [B*H, L, HD], folds 1/sqrt(HD) ----------------
__global__ void rope_inplace(unsigned short* __restrict__ Q) {
    int idx = blockIdx.x * 256 + threadIdx.x;          // B*H*L*(HD/2) = 1,048,576
    int p  = idx & 63;                                 // pair index 0..63
    int l  = (idx >> 6) & 255;
    int bh = idx >> 14;
    long base = (((long)bh * L_ + l) << 7) + 2 * p;
    float q1 = b2f(Q[base]), q2 = b2f(Q[base + 1]);
    float inv = powf(10000.0f, -(float)p * (1.0f / 64.0f));
    float ang = (float)l * inv;
    float s, c;
    sincosf(ang, &s, &c);
    const float sc = 0.08838834764831845f;             // 1/sqrt(128)
    Q[base]     = f2bf((q1 * c - q2 * s) * sc);
    Q[base + 1] = f2bf((q1 * s + q2 * c) * sc);
}

// ---------------- row softmax, in-place on bf16 rows of 2048 ----------------
__launch_bounds__(256)
__global__ void softmax_rows(unsigned short* __restrict__ S) {
    long row = blockIdx.x;
    unsigned short* p = S + row * 2048;
    int t = threadIdx.x, w = t >> 6, lane = t & 63;
    float v[8];
    float mx = -1e30f;
    #pragma unroll
    for (int i = 0; i < 8; i++) { v[i] = b2f(p[t + i * 256]); mx = fmaxf(mx, v[i]); }
    #pragma unroll
    for (int o = 32; o; o >>= 1) mx = fmaxf(mx, __shfl_xor(mx, o));
    __shared__ float redm[4], reds[4];
    if (lane == 0) redm[w] = mx;
    __syncthreads();
    mx = fmaxf(fmaxf(redm[0], redm[1]), fmaxf(redm[2], redm[3]));
    float sum = 0.f;
    #pragma unroll
    for (int i = 0; i < 8; i++) { v[i] = __expf(v[i] - mx); sum += v[i]; }
    #pragma unroll
    for (int o = 32; o; o >>= 1) sum += __shfl_xor(sum, o);
    if (lane == 0) reds[w] = sum;
    __syncthreads();
    sum = reds[0] + reds[1] + reds[2] + reds[3];
    float r = 1.0f / sum;
    #pragma unroll
    for (int i = 0; i < 8; i++) p[t + i * 256] = f2bf(v[i] * r);
}

// ---------------- combine PV split-K partials -> ctx_bf ----------------
// P layout: [s][bh][256][128] fp32, s in {0,1}. ctx_bf: [(b*256+m)*2048 + h*128 + d]
__global__ void combine_pv(const float* __restrict__ P, unsigned short* __restrict__ ctx) {
    int gid = blockIdx.x * 256 + threadIdx.x;          // 524288 threads, 4 floats each
    long e = (long)gid * 4;
    float4 a = *(const float4*)(P + e);
    float4 b = *(const float4*)(P + 2097152 + e);
    int bh = (int)(e >> 15);
    int m  = (int)((e >> 7) & 255);
    int d  = (int)(e & 127);
    int bb = bh >> 4, h = bh & 15;
    ushort4 o;
    o.x = f2bf(a.x + b.x); o.y = f2bf(a.y + b.y);
    o.z = f2bf(a.z + b.z); o.w = f2bf(a.w + b.w);
    *(ushort4*)(ctx + ((long)(bb * 256 + m)) * 2048 + h * 128 + d) = o;
}

// ---------------- bf16 GEMM: C[M,N] = A[M,K] * Bt[N,K]^T (+bias), batched ----------------
// EPI 0: fp32 plain [M,N] (+bias)                       -- fp32 LDS-bounce epilogue
// EPI 1: bf16 head relayout, rows = 1<<rpb_shift        -- bf16 LDS-bounce epilogue
// EPI 2: bf16 plain batched [z][M,N]                    -- bf16 LDS-bounce epilogue
// EPI 4: fp32 batched split-K partial [z][M,N]; z = s*64+bh; A/B offset by s*K along k
template <int EPI>
__launch_bounds__(256)
__global__ void gemm_bt(const unsigned short* __restrict__ A, const unsigned short* __restrict__ Bt,
                        const float* __restrict__ bias, void* __restrict__ out,
                        int M, int N, int K, int lda, int ldb,
                        long strideA, long strideB, int rpb_shift) {
    __shared__ __align__(16) unsigned short smem[8704];   // 17408 B
    unsigned short* As = smem;                            // 128x32
    unsigned short* Bs = smem + 4096;                     // 128x32
    const int z = blockIdx.z;
    const unsigned short* Ab;
    const unsigned short* Bb;
    if constexpr (EPI == 4) {
        int bh = z & 63, s = z >> 6;
        Ab = A + (long)bh * strideA + (long)s * K;
        Bb = Bt + (long)bh * strideB + (long)s * K;
    } else {
        Ab = A + (long)z * strideA;
        Bb = Bt + (long)z * strideB;
    }
    const int m0 = blockIdx.y * 128, n0 = blockIdx.x * 128;
    const int tid = threadIdx.x;
    const int w = tid >> 6, lane = tid & 63;
    const int quad = lane >> 4, l16 = lane & 15;
    const int wr = w >> 1, wc = w & 1;
    const int srow = lane >> 2;          // staging: row within 16-row chunk
    const int scol = (lane & 3) * 8;     // staging: k-offset (elements)

    f32x4 acc[4][4] = {};

    for (int k0 = 0; k0 < K; k0 += 32) {
        #pragma unroll
        for (int q = 0; q < 2; q++) {
            int ci = q * 4 + w;          // 1KB chunk id, 0..7
            int row = ci * 16 + srow;
            load_lds16(Ab + (long)(m0 + row) * lda + k0 + scol, (void*)(As + ci * 512));
            load_lds16(Bb + (long)(n0 + row) * ldb + k0 + scol, (void*)(Bs + ci * 512));
        }
        __syncthreads();
        bf16x8 af[4], bfr[4];
        #pragma unroll
        for (int i = 0; i < 4; i++) {
            int r = wr * 64 + i * 16 + l16;
            af[i] = *(const bf16x8*)(As + r * 32 + quad * 8);
        }
        #pragma unroll
        for (int j = 0; j < 4; j++) {
            int r = wc * 64 + j * 16 + l16;
            bfr[j] = *(const bf16x8*)(Bs + r * 32 + quad * 8);
        }
        #pragma unroll
        for (int i = 0; i < 4; i++)
            #pragma unroll
            for (int j = 0; j < 4; j++)
                acc[i][j] = __builtin_amdgcn_mfma_f32_16x16x32_bf16(af[i], bfr[j], acc[i][j], 0, 0, 0);
        __syncthreads();
    }

    // ---------------- epilogue via LDS bounce ----------------
    if constexpr (EPI == 1 || EPI == 2) {
        // bf16 bounce: smem as [64][136] ushort (272B rows, 16B-aligned; <=2-way bank)
        #pragma unroll
        for (int p = 0; p < 2; p++) {
            if (wr == p) {
                #pragma unroll
                for (int i = 0; i < 4; i++)
                    #pragma unroll
                    for (int j = 0; j < 4; j++)
                        #pragma unroll
                        for (int r = 0; r < 4; r++) {
                            int ml = i * 16 + quad * 4 + r;          // 0..63
                            int n  = wc * 64 + j * 16 + l16;         // 0..127
                            float v = acc[i][j][r];
                            if (bias) v += bias[n0 + n];
                            smem[ml * 136 + n] = f2bf(v);
                        }
            }
            __syncthreads();
            #pragma unroll
            for (int pass = 0; pass < 4; pass++) {
                int row = pass * 16 + (tid >> 4);                    // 0..63
                int seg = tid & 15;                                  // x8 elems
                bf16x8 val = *(const bf16x8*)(smem + row * 136 + seg * 8);
                int m = m0 + p * 64 + row;
                if constexpr (EPI == 1) {
                    int h = n0 >> 7;
                    long idx = (((long)(m >> rpb_shift) * 16 + h) << rpb_shift) + (m & ((1 << rpb_shift) - 1));
                    *(bf16x8*)((unsigned short*)out + (idx << 7) + seg * 8) = val;
                } else {
                    *(bf16x8*)((unsigned short*)out + (long)z * M * N + (long)m * N + n0 + seg * 8) = val;
                }
            }
            __syncthreads();
        }
    } else {
        // fp32 bounce: smem as [32][132] float (528B rows, 16B-aligned)
        float* smf = (float*)smem;
        #pragma unroll
        for (int q4 = 0; q4 < 4; q4++) {
            if (wr == (q4 >> 1)) {
                #pragma unroll
                for (int ii = 0; ii < 2; ii++) {
                    int i = (q4 & 1) * 2 + ii;
                    #pragma unroll
                    for (int j = 0; j < 4; j++)
                        #pragma unroll
                        for (int r = 0; r < 4; r++) {
                            int ml = ii * 16 + quad * 4 + r;         // 0..31
                            int n  = wc * 64 + j * 16 + l16;
                            float v = acc[i][j][r];
                            if (bias) v += bias[n0 + n];
                            smf[ml * 132 + n] = v;
                        }
                }
            }
            __syncthreads();
            #pragma unroll
            for (int pass = 0; pass < 4; pass++) {
                int row = pass * 8 + (tid >> 5);                     // 0..31
                int seg = tid & 31;                                  // x4 floats
                float4 val = *(const float4*)(smf + row * 132 + seg * 4);
                int m = m0 + q4 * 32 + row;
                if constexpr (EPI == 0) {
                    *(float4*)((float*)out + (long)m * N + n0 + seg * 4) = val;
                } else {
                    *(float4*)((float*)out + (long)z * M * N + (long)m * N + n0 + seg * 4) = val;
                }
            }
            __syncthreads();
        }
    }
}

extern "C" void kernel_launch(void* const* d_in, const int* in_sizes, int n_in,
                              void* d_out, int out_size, void* d_ws, size_t ws_size,
                              hipStream_t stream) {
    const float* x   = (const float*)d_in[0];   // [4,256,2048]
    const float* enc = (const float*)d_in[1];   // [4,2048,1024]
    const float* Wq  = (const float*)d_in[2];   // [2048,2048]
    const float* bq  = (const float*)d_in[3];
    const float* Wk  = (const float*)d_in[4];   // [1024,2048]
    const float* bk  = (const float*)d_in[5];
    const float* Wv  = (const float*)d_in[6];   // [1024,2048]
    const float* bv  = (const float*)d_in[7];
    const float* Wo  = (const float*)d_in[8];   // [2048,2048]
    const float* bo  = (const float*)d_in[9];
    float* out = (float*)d_out;                 // [4,256,2048] fp32

    char* ws = (char*)d_ws;
    size_t o = 0;
    unsigned short* x_bf   = (unsigned short*)(ws + o); o += 2097152ULL * 2;   // [1024,2048]
    unsigned short* enc_bf = (unsigned short*)(ws + o); o += 8388608ULL * 2;   // [8192,1024]
    unsigned short* WqT    = (unsigned short*)(ws + o); o += 4194304ULL * 2;   // [2048,2048]
    unsigned short* WkT    = (unsigned short*)(ws + o); o += 2097152ULL * 2;   // [2048,1024]
    unsigned short* WvT    = (unsigned short*)(ws + o); o += 2097152ULL * 2;   // [2048,1024]
    unsigned short* WoT    = (unsigned short*)(ws + o); o += 4194304ULL * 2;   // [2048,2048]
    unsigned short* Q_bf   = (unsigned short*)(ws + o); o += 2097152ULL * 2;   // [64,256,128]
    unsigned short* K_bf   = (unsigned short*)(ws + o); o += 16777216ULL * 2;  // [64,2048,128]
    unsigned short* V_bf   = (unsigned short*)(ws + o); o += 16777216ULL * 2;  // [64,2048,128]
    unsigned short* Vt     = (unsigned short*)(ws + o); o += 16777216ULL * 2;  // [64,128,2048]
    unsigned short* S_bf   = (unsigned short*)(ws + o); o += 33554432ULL * 2;  // [64,256,2048]
    unsigned short* ctx_bf = (unsigned short*)(ws + o); o += 2097152ULL * 2;   // [1024,2048]
    // PV split-K partials (33.5 MB) overlay the front region (x_bf..WvT = 36 MB),
    // all dead before the PV GEMM runs.
    float* Pbuf = (float*)ws;                                                  // [2][64][256][128] fp32

    dim3 tb(32, 8);

    // casts
    cast_f32_bf16<<<2048, 256, 0, stream>>>(x, x_bf, 2097152);
    cast_f32_bf16<<<8192, 256, 0, stream>>>(enc, enc_bf, 8388608);

    // weight transposes (fp32 [K,N] -> bf16 [N,K])
    transpose_f32_bf16<<<dim3(64, 64), tb, 0, stream>>>(Wq, WqT, 2048, 2048);
    transpose_f32_bf16<<<dim3(64, 32), tb, 0, stream>>>(Wk, WkT, 1024, 2048);
    transpose_f32_bf16<<<dim3(64, 32), tb, 0, stream>>>(Wv, WvT, 1024, 2048);
    transpose_f32_bf16<<<dim3(64, 64), tb, 0, stream>>>(Wo, WoT, 2048, 2048);

    // Q = x @ Wq + bq -> head layout bf16 [B,H,L,HD]
    gemm_bt<1><<<dim3(16, 8, 1), 256, 0, stream>>>(x_bf, WqT, bq, Q_bf,
                                                   1024, 2048, 2048, 2048, 2048, 0, 0, 8);
    // RoPE in place (+ fold 1/sqrt(HD))
    rope_inplace<<<4096, 256, 0, stream>>>(Q_bf);

    // K,V = enc @ Wk/Wv + b -> head layout bf16 [B,H,LE,HD]
    gemm_bt<1><<<dim3(16, 64, 1), 256, 0, stream>>>(enc_bf, WkT, bk, K_bf,
                                                    8192, 2048, 1024, 1024, 1024, 0, 0, 11);
    gemm_bt<1><<<dim3(16, 64, 1), 256, 0, stream>>>(enc_bf, WvT, bv, V_bf,
                                                    8192, 2048, 1024, 1024, 1024, 0, 0, 11);

    // V -> Vt  [B,H,HD,LE]
    transpose_bf16_batched<<<dim3(4, 64, 64), tb, 0, stream>>>(V_bf, Vt, 2048, 128);

    // S = Q @ K^T (scale folded into Q) -> bf16 [64,256,2048]
    gemm_bt<2><<<dim3(16, 2, 64), 256, 0, stream>>>(Q_bf, K_bf, nullptr, S_bf,
                                                    256, 2048, 128, 128, 128,
                                                    256 * 128, 2048 * 128, 0);
    // softmax rows
    softmax_rows<<<16384, 256, 0, stream>>>(S_bf);

    // ctx partials = P @ V, split-K=2 over le: grid z = s*64+bh
    gemm_bt<4><<<dim3(1, 2, 128), 256, 0, stream>>>(S_bf, Vt, nullptr, Pbuf,
                                                    256, 128, 1024, 2048, 2048,
                                                    256 * 2048, 128 * 2048, 0);
    combine_pv<<<2048, 256, 0, stream>>>(Pbuf, ctx_bf);

    // out = ctx @ Wo + bo -> fp32
    gemm_bt<0><<<dim3(16, 8, 1), 256, 0, stream>>>(ctx_bf, WoT, bo, out,
                                                   1024, 2048, 2048, 2048, 2048, 0, 0, 0);
}

// Round 3
// 404.164 us; speedup vs baseline: 1.2881x; 1.2871x over previous
//
#include <hip/hip_runtime.h>

// CrossAttention: B=4, L=256, D=2048, LE=2048, DE=1024, H=16, HD=128
// R3: single-barrier double-buffered K-loop (prefetch after barrier),
//     fused K+V projection GEMM, split-K=2 for Q/O/PV, rope folded into
//     Q-combine, vectorized softmax.

#define B_ 4
#define L_ 256
#define D_ 2048
#define LE_ 2048
#define DE_ 1024
#define H_ 16
#define HD_ 128

using f32x4  = __attribute__((ext_vector_type(4))) float;
using bf16x8 = __attribute__((ext_vector_type(8))) short;

__device__ __forceinline__ unsigned short f2bf(float f) {
    union { float f; unsigned int u; } v; v.f = f;
    unsigned int r = v.u + 0x7fffu + ((v.u >> 16) & 1u);   // RNE
    return (unsigned short)(r >> 16);
}
__device__ __forceinline__ float b2f(unsigned short h) {
    union { unsigned int u; float f; } v; v.u = ((unsigned int)h) << 16;
    return v.f;
}

__device__ __forceinline__ void load_lds16(const void* g, void* l) {
    __builtin_amdgcn_global_load_lds((const __attribute__((address_space(1))) void*)g,
                                     (__attribute__((address_space(3))) void*)l, 16, 0, 0);
}

// ---------------- elementwise cast fp32 -> bf16 (vec4) ----------------
__global__ void cast_f32_bf16(const float* __restrict__ in, unsigned short* __restrict__ out, int n) {
    int i = (blockIdx.x * 256 + threadIdx.x) * 4;
    if (i < n) {
        float4 v = *(const float4*)(in + i);
        ushort4 o;
        o.x = f2bf(v.x); o.y = f2bf(v.y); o.z = f2bf(v.z); o.w = f2bf(v.w);
        *(ushort4*)(out + i) = o;
    }
}

// ---------------- tiled transpose fp32[R,C] -> bf16[C,R] ----------------
__global__ void transpose_f32_bf16(const float* __restrict__ in, unsigned short* __restrict__ out,
                                   int R, int C) {
    __shared__ float t[32][33];
    int r0 = blockIdx.y * 32, c0 = blockIdx.x * 32;
    int tx = threadIdx.x, ty = threadIdx.y;            // block (32,8)
    #pragma unroll
    for (int i = 0; i < 32; i += 8) t[ty + i][tx] = in[(long)(r0 + ty + i) * C + c0 + tx];
    __syncthreads();
    #pragma unroll
    for (int i = 0; i < 32; i += 8) out[(long)(c0 + ty + i) * R + r0 + tx] = f2bf(t[tx][ty + i]);
}

// ---------------- tiled transpose bf16[R,C] -> bf16[C,R], batched (z) ----------------
__global__ void transpose_bf16_batched(const unsigned short* __restrict__ in,
                                       unsigned short* __restrict__ out, int R, int C) {
    __shared__ unsigned short t[32][33];
    long zo = (long)blockIdx.z * R * C;
    int r0 = blockIdx.y * 32, c0 = blockIdx.x * 32;
    int tx = threadIdx.x, ty = threadIdx.y;            // block (32,8)
    #pragma unroll
    for (int i = 0; i < 32; i += 8) t[ty + i][tx] = in[zo + (long)(r0 + ty + i) * C + c0 + tx];
    __syncthreads();
    #pragma unroll
    for (int i = 0; i < 32; i += 8) out[zo + (long)(c0 + ty + i) * R + r0 + tx] = t[tx][ty + i];
}

// ---------------- combine Q split-K partials + bias + RoPE -> Q_bf head layout ----------------
// P: [2][1024][2048] fp32 (m = b*256+l, n = h*128+d). Q_bf: [(b*16+h)*256+l][128]
__global__ void combine_q_rope(const float* __restrict__ P, const float* __restrict__ bq,
                               unsigned short* __restrict__ Q) {
    int gid = blockIdx.x * 256 + threadIdx.x;          // 1,048,576 pairs
    int p = gid & 63;
    int h = (gid >> 6) & 15;
    int m = gid >> 10;                                 // 0..1023
    int n = h * 128 + 2 * p;
    long i0 = (long)m * 2048 + n;
    float2 a  = *(const float2*)(P + i0);
    float2 b2 = *(const float2*)(P + 2097152 + i0);
    float q1 = a.x + b2.x + bq[n];
    float q2 = a.y + b2.y + bq[n + 1];
    int l = m & 255, b = m >> 8;
    float inv = powf(10000.0f, -(float)p * (1.0f / 64.0f));
    float s, c;
    sincosf((float)l * inv, &s, &c);
    const float sc = 0.08838834764831845f;             // 1/sqrt(128)
    long qi = (((long)(b * 16 + h) * 256 + l) << 7) + 2 * p;
    ushort2 o;
    o.x = f2bf((q1 * c - q2 * s) * sc);
    o.y = f2bf((q1 * s + q2 * c) * sc);
    *(ushort2*)(Q + qi) = o;
}

// ---------------- combine PV split-K partials -> ctx_bf ----------------
// P: [2][64][256][128] fp32. ctx_bf: [(b*256+m)*2048 + h*128 + d]
__global__ void combine_pv(const float* __restrict__ P, unsigned short* __restrict__ ctx) {
    int gid = blockIdx.x * 256 + threadIdx.x;          // 524288 threads, 4 floats each
    long e = (long)gid * 4;
    float4 a = *(const float4*)(P + e);
    float4 b = *(const float4*)(P + 2097152 + e);
    int bh = (int)(e >> 15);
    int m  = (int)((e >> 7) & 255);
    int d  = (int)(e & 127);
    int bb = bh >> 4, h = bh & 15;
    ushort4 o;
    o.x = f2bf(a.x + b.x); o.y = f2bf(a.y + b.y);
    o.z = f2bf(a.z + b.z); o.w = f2bf(a.w + b.w);
    *(ushort4*)(ctx + ((long)(bb * 256 + m)) * 2048 + h * 128 + d) = o;
}

// ---------------- combine O split-K partials + bias -> fp32 out ----------------
__global__ void combine_o(const float* __restrict__ P, const float* __restrict__ bo,
                          float* __restrict__ out) {
    int gid = blockIdx.x * 256 + threadIdx.x;          // 524288
    long e = (long)gid * 4;
    float4 a = *(const float4*)(P + e);
    float4 b = *(const float4*)(P + 2097152 + e);
    int n = (int)(e & 2047);
    float4 bb = *(const float4*)(bo + n);
    float4 r;
    r.x = a.x + b.x + bb.x; r.y = a.y + b.y + bb.y;
    r.z = a.z + b.z + bb.z; r.w = a.w + b.w + bb.w;
    *(float4*)(out + e) = r;
}

// ---------------- row softmax, in-place on bf16 rows of 2048 (16B/thread) ----------------
__launch_bounds__(256)
__global__ void softmax_rows(unsigned short* __restrict__ S) {
    long row = blockIdx.x;
    unsigned short* p = S + row * 2048;
    int t = threadIdx.x, w = t >> 6, lane = t & 63;
    bf16x8 raw = *(const bf16x8*)(p + t * 8);
    float v[8];
    float mx = -1e30f;
    #pragma unroll
    for (int i = 0; i < 8; i++) { v[i] = b2f((unsigned short)raw[i]); mx = fmaxf(mx, v[i]); }
    #pragma unroll
    for (int o = 32; o; o >>= 1) mx = fmaxf(mx, __shfl_xor(mx, o));
    __shared__ float redm[4], reds[4];
    if (lane == 0) redm[w] = mx;
    __syncthreads();
    mx = fmaxf(fmaxf(redm[0], redm[1]), fmaxf(redm[2], redm[3]));
    float sum = 0.f;
    #pragma unroll
    for (int i = 0; i < 8; i++) { v[i] = __expf(v[i] - mx); sum += v[i]; }
    #pragma unroll
    for (int o = 32; o; o >>= 1) sum += __shfl_xor(sum, o);
    if (lane == 0) reds[w] = sum;
    __syncthreads();
    sum = reds[0] + reds[1] + reds[2] + reds[3];
    float r = 1.0f / sum;
    bf16x8 res;
    #pragma unroll
    for (int i = 0; i < 8; i++) res[i] = (short)f2bf(v[i] * r);
    *(bf16x8*)(p + t * 8) = res;
}

// ---------------- bf16 GEMM: C[M,N] = A[M,K] * Bt[N,K]^T, batched / split-K ----------------
// Single-barrier double-buffered K-loop: prefetch tile i+1 issued AFTER the
// barrier of iter i; the compiler's vmcnt(0) drain before s_barrier then waits
// on loads issued one compute-phase earlier.
// EPI 1: bf16 KV head relayout; n<nsplit -> outA(K_bf)+biasA, else outB(V_bf)+biasB
// EPI 2: bf16 plain batched [z][M,N]
// EPI 4: fp32 split-K partial; z -> s=z/zdiv, bh=z%zdiv; out[(s*zdiv+bh)][M][N]
template <int EPI>
__launch_bounds__(256)
__global__ void gemm_bt(const unsigned short* __restrict__ A, const unsigned short* __restrict__ Bt,
                        const float* __restrict__ biasA, const float* __restrict__ biasB,
                        void* __restrict__ outA, void* __restrict__ outB,
                        int M, int N, int K, int lda, int ldb,
                        long strideA, long strideB, int zdiv, int nsplit) {
    __shared__ __align__(16) unsigned short smem[16384];  // 32 KB: A0 B0 A1 B1 (8KB each)
    const int z = blockIdx.z;
    int s = 0, bh = z;
    if constexpr (EPI == 4) { s = z / zdiv; bh = z - s * zdiv; }
    const unsigned short* Ab = A + (long)bh * strideA + (long)s * K;
    const unsigned short* Bb = Bt + (long)bh * strideB + (long)s * K;
    const int m0 = blockIdx.y * 128, n0 = blockIdx.x * 128;
    const int tid = threadIdx.x;
    const int w = tid >> 6, lane = tid & 63;
    const int quad = lane >> 4, l16 = lane & 15;
    const int wr = w >> 1, wc = w & 1;
    const int srow = lane >> 2;          // staging: row within 16-row chunk
    const int scol = (lane & 3) * 8;     // staging: k-offset (elements)

    f32x4 acc[4][4] = {};

    auto stage = [&](int k0, int p) {
        unsigned short* As = smem + p * 8192;
        unsigned short* Bs = As + 4096;
        #pragma unroll
        for (int q = 0; q < 2; q++) {
            int ci = q * 4 + w;          // 1KB chunk id, 0..7
            int row = ci * 16 + srow;
            load_lds16(Ab + (long)(m0 + row) * lda + k0 + scol, (void*)(As + ci * 512));
            load_lds16(Bb + (long)(n0 + row) * ldb + k0 + scol, (void*)(Bs + ci * 512));
        }
    };

    const int nk = K >> 5;
    stage(0, 0);
    for (int i = 0; i < nk; i++) {
        __syncthreads();                 // drains prefetch issued in iter i-1
        if (i + 1 < nk) stage((i + 1) << 5, (i + 1) & 1);
        const unsigned short* As = smem + (i & 1) * 8192;
        const unsigned short* Bs = As + 4096;
        bf16x8 af[4], bfr[4];
        #pragma unroll
        for (int ii = 0; ii < 4; ii++) {
            int r = wr * 64 + ii * 16 + l16;
            af[ii] = *(const bf16x8*)(As + r * 32 + quad * 8);
        }
        #pragma unroll
        for (int j = 0; j < 4; j++) {
            int r = wc * 64 + j * 16 + l16;
            bfr[j] = *(const bf16x8*)(Bs + r * 32 + quad * 8);
        }
        #pragma unroll
        for (int ii = 0; ii < 4; ii++)
            #pragma unroll
            for (int j = 0; j < 4; j++)
                acc[ii][j] = __builtin_amdgcn_mfma_f32_16x16x32_bf16(af[ii], bfr[j], acc[ii][j], 0, 0, 0);
    }
    __syncthreads();                     // smem reuse for epilogue

    // ---------------- epilogue via LDS bounce ----------------
    if constexpr (EPI == 1 || EPI == 2) {
        const bool second = (EPI == 1) && (n0 >= nsplit);
        const float* bias = second ? biasB : biasA;
        const int n0e = second ? n0 - nsplit : n0;
        unsigned short* dst = (unsigned short*)(second ? outB : outA);
        #pragma unroll
        for (int p = 0; p < 2; p++) {
            if (wr == p) {
                #pragma unroll
                for (int i = 0; i < 4; i++)
                    #pragma unroll
                    for (int j = 0; j < 4; j++)
                        #pragma unroll
                        for (int r = 0; r < 4; r++) {
                            int ml = i * 16 + quad * 4 + r;          // 0..63
                            int n  = wc * 64 + j * 16 + l16;         // 0..127
                            float v = acc[i][j][r];
                            if (bias) v += bias[n0e + n];
                            smem[ml * 136 + n] = f2bf(v);
                        }
            }
            __syncthreads();
            #pragma unroll
            for (int pass = 0; pass < 4; pass++) {
                int row = pass * 16 + (tid >> 4);                    // 0..63
                int seg = tid & 15;                                  // x8 elems
                bf16x8 val = *(const bf16x8*)(smem + row * 136 + seg * 8);
                int m = m0 + p * 64 + row;
                if constexpr (EPI == 1) {
                    int h = n0e >> 7;                                // 0..15
                    int b = m >> 11, mrow = m & 2047;
                    long idx = (((long)(b * 16 + h)) << 11) + mrow;
                    *(bf16x8*)(dst + (idx << 7) + seg * 8) = val;
                } else {
                    *(bf16x8*)((unsigned short*)outA + (long)z * M * N + (long)m * N + n0 + seg * 8) = val;
                }
            }
            __syncthreads();
        }
    } else {
        // fp32 split-K partial
        float* smf = (float*)smem;
        long zo = ((long)s * zdiv + bh) * (long)M * N;
        #pragma unroll
        for (int q4 = 0; q4 < 4; q4++) {
            if (wr == (q4 >> 1)) {
                #pragma unroll
                for (int ii = 0; ii < 2; ii++) {
                    int i = (q4 & 1) * 2 + ii;
                    #pragma unroll
                    for (int j = 0; j < 4; j++)
                        #pragma unroll
                        for (int r = 0; r < 4; r++) {
                            int ml = ii * 16 + quad * 4 + r;         // 0..31
                            int n  = wc * 64 + j * 16 + l16;
                            smf[ml * 132 + n] = acc[i][j][r];
                        }
                }
            }
            __syncthreads();
            #pragma unroll
            for (int pass = 0; pass < 4; pass++) {
                int row = pass * 8 + (tid >> 5);                     // 0..31
                int seg = tid & 31;                                  // x4 floats
                float4 val = *(const float4*)(smf + row * 132 + seg * 4);
                int m = m0 + q4 * 32 + row;
                *(float4*)((float*)outA + zo + (long)m * N + n0 + seg * 4) = val;
            }
            __syncthreads();
        }
    }
}

extern "C" void kernel_launch(void* const* d_in, const int* in_sizes, int n_in,
                              void* d_out, int out_size, void* d_ws, size_t ws_size,
                              hipStream_t stream) {
    const float* x   = (const float*)d_in[0];   // [4,256,2048]
    const float* enc = (const float*)d_in[1];   // [4,2048,1024]
    const float* Wq  = (const float*)d_in[2];   // [2048,2048]
    const float* bq  = (const float*)d_in[3];
    const float* Wk  = (const float*)d_in[4];   // [1024,2048]
    const float* bk  = (const float*)d_in[5];
    const float* Wv  = (const float*)d_in[6];   // [1024,2048]
    const float* bv  = (const float*)d_in[7];
    const float* Wo  = (const float*)d_in[8];   // [2048,2048]
    const float* bo  = (const float*)d_in[9];
    float* out = (float*)d_out;                 // [4,256,2048] fp32

    // ws layout (MB offsets), with liveness-based overlays:
    //   0: x_bf(4) | 4: enc_bf(16) | 20: WqT(8) | 28: WkvT(8) | 36: V_bf(32)
    //  68: K_bf(32) | 100: WoT(8) | 108: Q_bf(4) | 112: Vt(64)
    //  S_bf(64) overlays 0..64 (x/enc/WqT/WkvT dead by S-GEMM)
    //  Pq(16) overlays 36 (V_bf region, dead until KV-proj)
    //  Ppv(16.8) overlays 68 (K_bf, dead after S-GEMM)
    //  Po(16) overlays 0 (S_bf, dead after PV)
    //  ctx_bf(4) overlays 108 (Q_bf, dead after S-GEMM)
    char* ws = (char*)d_ws;
    const size_t MB = 1024 * 1024;
    unsigned short* x_bf   = (unsigned short*)(ws + 0 * MB);
    unsigned short* enc_bf = (unsigned short*)(ws + 4 * MB);
    unsigned short* WqT    = (unsigned short*)(ws + 20 * MB);
    unsigned short* WkvT   = (unsigned short*)(ws + 28 * MB);
    unsigned short* V_bf   = (unsigned short*)(ws + 36 * MB);
    unsigned short* K_bf   = (unsigned short*)(ws + 68 * MB);
    unsigned short* WoT    = (unsigned short*)(ws + 100 * MB);
    unsigned short* Q_bf   = (unsigned short*)(ws + 108 * MB);
    unsigned short* Vt     = (unsigned short*)(ws + 112 * MB);
    unsigned short* S_bf   = (unsigned short*)(ws + 0 * MB);
    float*          Pq     = (float*)(ws + 36 * MB);
    float*          Ppv    = (float*)(ws + 68 * MB);
    float*          Po     = (float*)(ws + 0 * MB);
    unsigned short* ctx_bf = (unsigned short*)(ws + 108 * MB);

    dim3 tb(32, 8);

    // casts
    cast_f32_bf16<<<2048, 256, 0, stream>>>(x, x_bf, 2097152);
    cast_f32_bf16<<<8192, 256, 0, stream>>>(enc, enc_bf, 8388608);

    // weight transposes (fp32 [K,N] -> bf16 [N,K]); Wk/Wv stacked into WkvT [4096,1024]
    transpose_f32_bf16<<<dim3(64, 64), tb, 0, stream>>>(Wq, WqT, 2048, 2048);
    transpose_f32_bf16<<<dim3(64, 32), tb, 0, stream>>>(Wk, WkvT, 1024, 2048);
    transpose_f32_bf16<<<dim3(64, 32), tb, 0, stream>>>(Wv, WkvT + 2048 * 1024, 1024, 2048);
    transpose_f32_bf16<<<dim3(64, 64), tb, 0, stream>>>(Wo, WoT, 2048, 2048);

    // Q partials = x @ Wq, split-K=2 -> Pq[2][1024][2048]
    gemm_bt<4><<<dim3(16, 8, 2), 256, 0, stream>>>(x_bf, WqT, nullptr, nullptr, Pq, nullptr,
                                                   1024, 2048, 1024, 2048, 2048, 0, 0, 1, 0);
    // combine + bias + RoPE + scale -> Q_bf head layout
    combine_q_rope<<<4096, 256, 0, stream>>>(Pq, bq, Q_bf);

    // K|V = enc @ [Wk|Wv] + bias -> head layouts (fused, N=4096)
    gemm_bt<1><<<dim3(32, 64, 1), 256, 0, stream>>>(enc_bf, WkvT, bk, bv, K_bf, V_bf,
                                                    8192, 4096, 1024, 1024, 1024, 0, 0, 1, 2048);

    // V -> Vt [B,H,HD,LE]
    transpose_bf16_batched<<<dim3(4, 64, 64), tb, 0, stream>>>(V_bf, Vt, 2048, 128);

    // S = Q @ K^T (scale folded into Q) -> bf16 [64][256][2048]
    gemm_bt<2><<<dim3(16, 2, 64), 256, 0, stream>>>(Q_bf, K_bf, nullptr, nullptr, S_bf, nullptr,
                                                    256, 2048, 128, 128, 128,
                                                    256 * 128, 2048 * 128, 1, 0);
    // softmax rows
    softmax_rows<<<16384, 256, 0, stream>>>(S_bf);

    // ctx partials = P @ V, split-K=2: z = s*64+bh -> Ppv[2][64][256][128]
    gemm_bt<4><<<dim3(1, 2, 128), 256, 0, stream>>>(S_bf, Vt, nullptr, nullptr, Ppv, nullptr,
                                                    256, 128, 1024, 2048, 2048,
                                                    256 * 2048, 128 * 2048, 64, 0);
    combine_pv<<<2048, 256, 0, stream>>>(Ppv, ctx_bf);

    // O partials = ctx @ Wo, split-K=2 -> Po[2][1024][2048]
    gemm_bt<4><<<dim3(16, 8, 2), 256, 0, stream>>>(ctx_bf, WoT, nullptr, nullptr, Po, nullptr,
                                                   1024, 2048, 1024, 2048, 2048, 0, 0, 1, 0);
    combine_o<<<2048, 256, 0, stream>>>(Po, bo, out);
}